// Round 12
// baseline (245.011 us; speedup 1.0000x reference)
//
#include <hip/hip_runtime.h>
#include <hip/hip_bf16.h>

typedef __attribute__((ext_vector_type(4))) int i32x4;

#define B_N 1024
#define D_K 512
#define C_N 100000
#define SCALE_F 64.0f
#define MARGIN_F 0.35f
#define BM 128
#define BN 256
#define BKB 128      // K-tile in BYTES per row (= 128 i8 elements)
#define NGRP 391     // 256-row W groups == N-tiles
#define GRID 512     // exactly 2 blocks/CU -> all co-resident (spin-safe)
#define MAXL 64.0f   // global logit bound: |cos|*64 <= 64 (+quant eps, harmless)
#define LOG2E 1.4426950408889634f
#define KQ2 (SCALE_F / (127.0f * 127.0f) * LOG2E)   // base-2 scale
#define MAXL2 (MAXL * LOG2E)

__device__ __forceinline__ float dot4(float4 a, float4 b) {
    return a.x * b.x + a.y * b.y + a.z * b.z + a.w * b.w;
}
__device__ __forceinline__ float amax4(float4 a) {
    return fmaxf(fmaxf(fabsf(a.x), fabsf(a.y)), fmaxf(fabsf(a.z), fabsf(a.w)));
}
__device__ __forceinline__ int packq(float v0, float v1, float v2, float v3, float qs) {
    int q0 = __float2int_rn(v0 * qs), q1 = __float2int_rn(v1 * qs);
    int q2 = __float2int_rn(v2 * qs), q3 = __float2int_rn(v3 * qs);
    return (q0 & 0xFF) | ((q1 & 0xFF) << 8) | ((q2 & 0xFF) << 16) | ((q3 & 0xFF) << 24);
}

// ------- kernel A: fused norm_x -> i8 quantize + disc loss + target logit
//         + zero rowsum + zero flags (stream-ordered before the fused gemm) -------
__global__ void normx_disc_kernel(const float* __restrict__ x,
                                  const int* __restrict__ target,
                                  const float* __restrict__ ida,
                                  const float* __restrict__ bmat,
                                  char* __restrict__ xq,
                                  float* __restrict__ sx,
                                  float* __restrict__ dpart,
                                  float* __restrict__ tlogit,
                                  float* __restrict__ rowsum,
                                  int* __restrict__ flags) {
    int gid = blockIdx.x * 256 + threadIdx.x;
    if (gid < NGRP) flags[gid] = 0;

    int row = blockIdx.x * 4 + (threadIdx.x >> 6);
    int l = threadIdx.x & 63;
    long t = (long)target[row];
    const float4* xp = (const float4*)(x + (size_t)row * D_K);
    const float4* wp = (const float4*)(ida + (size_t)t * D_K);
    const float4* bp = (const float4*)(bmat + (size_t)t * D_K);
    float4 x0 = xp[l], x1 = xp[64 + l];
    float4 w0 = wp[l], w1 = wp[64 + l];
    float4 b0 = bp[l], b1 = bp[64 + l];
    float xssq = dot4(x0, x0) + dot4(x1, x1);
    float wssq = dot4(w0, w0) + dot4(w1, w1);
    float bssq = dot4(b0, b0) + dot4(b1, b1);
    float xmx = fmaxf(amax4(x0), amax4(x1));
#pragma unroll
    for (int m = 1; m < 64; m <<= 1) {
        xssq += __shfl_xor(xssq, m);
        wssq += __shfl_xor(wssq, m);
        bssq += __shfl_xor(bssq, m);
        xmx = fmaxf(xmx, __shfl_xor(xmx, m));
    }
    float xinv = 1.0f / fmaxf(sqrtf(xssq), 1e-12f);
    float winv = 1.0f / fmaxf(sqrtf(wssq), 1e-12f);
    float btn = sqrtf(bssq);
    float cs = fminf(btn, 0.05f) / fmaxf(btn, 1e-12f);

    // quantize normalized x to i8 with per-row scale sxm = max|x_n|
    float sxm = fmaxf(xmx * xinv, 1e-12f);
    float qs = 127.0f / sxm * xinv;     // applied to RAW x
    int* oq = (int*)(xq + (size_t)row * D_K);
    oq[l] = packq(x0.x, x0.y, x0.z, x0.w, qs);
    oq[64 + l] = packq(x1.x, x1.y, x1.z, x1.w, qs);

    float xs[8] = {x0.x, x0.y, x0.z, x0.w, x1.x, x1.y, x1.z, x1.w};
    float wv[8] = {w0.x, w0.y, w0.z, w0.w, w1.x, w1.y, w1.z, w1.w};
    float bv[8] = {b0.x, b0.y, b0.z, b0.w, b1.x, b1.y, b1.z, b1.w};
    float rss = 0.0f, dt = 0.0f;
#pragma unroll
    for (int i = 0; i < 8; ++i) {
        float xn = xs[i] * xinv;
        float wn = wv[i] * winv;
        float d = xn - wn;
        float r = d - bv[i] * cs;
        rss += r * r;
        dt += xn * wn;
    }
#pragma unroll
    for (int m = 1; m < 64; m <<= 1) {
        rss += __shfl_xor(rss, m);
        dt += __shfl_xor(dt, m);
    }
    if (l == 0) {
        sx[row] = sxm;
        dpart[row] = sqrtf(rss);
        tlogit[row] = SCALE_F * dt;
        rowsum[row] = 0.0f;     // zero before gemm's atomics (stream-ordered)
    }
}

// ------------- kernel B: FUSED producer/consumer: W-quantize (overlapped) + i8 GEMM -------------
// Blocks 0..390 first quantize one 256-row W group (HBM-bound, ~32 us aggregate),
// release flags[g]; all 512 blocks then consume 6-7 tiles each, acquire-spinning
// on the tile's group flag. Grid == resident capacity (2 blocks/CU) -> spin-safe.
__global__ __launch_bounds__(256, 2) void fused_gemm_kernel(const char* __restrict__ A,
                                                            const float* __restrict__ Wf,
                                                            const float* __restrict__ sx,
                                                            char* __restrict__ wq,
                                                            float* __restrict__ sw,
                                                            int* __restrict__ flags,
                                                            float* __restrict__ rowsum) {
    __shared__ char As[BM * BKB];   // 16 KB
    __shared__ char Bs[BN * BKB];   // 32 KB
    __shared__ float sxl[BM];
    __shared__ float swl[BN];
    __shared__ float rs[2][BM];

    int tid = threadIdx.x;
    int wave = tid >> 6, l = tid & 63;
    int wm = wave >> 1, wn = wave & 1;   // 2 M-waves x 2 N-waves, wave-tile 64x128
    int cl = l & 15, hi = l >> 4;
    int b = blockIdx.x;

    // ---------------- production phase: quantize W group b ----------------
    if (b < NGRP) {
#pragma unroll 1
        for (int it = 0; it < 64; ++it) {
            int row = b * 256 + it * 4 + wave;
            if (row < C_N) {
                const float4* rp = (const float4*)(Wf + (size_t)row * D_K);
                float4 a = rp[l], bb = rp[64 + l];
                float ssq = dot4(a, a) + dot4(bb, bb);
                float mx = fmaxf(amax4(a), amax4(bb));
#pragma unroll
                for (int m = 1; m < 64; m <<= 1) {
                    ssq += __shfl_xor(ssq, m);
                    mx = fmaxf(mx, __shfl_xor(mx, m));
                }
                float inv = 1.0f / fmaxf(sqrtf(ssq), 1e-12f);
                float swm = fmaxf(mx * inv, 1e-12f);
                float qs = 127.0f / swm * inv;
                int* oq = (int*)(wq + (size_t)row * D_K);
                oq[l] = packq(a.x, a.y, a.z, a.w, qs);
                oq[64 + l] = packq(bb.x, bb.y, bb.z, bb.w, qs);
                if (l == 0) sw[row] = swm;
            }
        }
        __syncthreads();   // all waves' stores issued & drained (barrier waits vmcnt)
        if (tid == 0)
            __hip_atomic_store(&flags[b], 1, __ATOMIC_RELEASE, __HIP_MEMORY_SCOPE_AGENT);
    }

    // ---------------- consumption phase: 6-7 tiles per block ----------------
    int c = b & 7, j = b >> 3;               // XCD chunk + local index
    int srow = l >> 3;                       // row 0..7 within an 8-row staging chunk
    int scolB = ((l & 7) ^ (l >> 3)) * 16;   // pre-swizzled source byte slot (rule #21)

#pragma unroll 1
    for (int i = j; i < NGRP; i += 64) {
        int wgid = c * NGRP + i;             // XCD-contiguous tile-space (nt major, mt minor)
        int nt = wgid >> 3, mt = wgid & 7;
        int m0 = mt * BM, n0 = nt * BN;

        if (tid == 0) {
            while (__hip_atomic_load(&flags[nt], __ATOMIC_ACQUIRE, __HIP_MEMORY_SCOPE_AGENT) == 0)
                __builtin_amdgcn_s_sleep(2);
        }
        __syncthreads();

        // per-tile scale tiles
        {
            int cc = n0 + tid;
            swl[tid] = sw[cc < C_N ? cc : C_N - 1];
            if (tid < BM) sxl[tid] = sx[m0 + tid];
        }

        i32x4 acc[4][8];
#pragma unroll
        for (int mi = 0; mi < 4; ++mi)
#pragma unroll
            for (int ni = 0; ni < 8; ++ni) acc[mi][ni] = (i32x4){0, 0, 0, 0};

#pragma unroll 1
        for (int kt = 0; kt < 4; ++kt) {     // 4 K-tiles of 128 i8
#pragma unroll
            for (int u = 0; u < 4; ++u) {    // A: 128 rows = 4 chunks/wave
                int rb = wave * 32 + u * 8;
                const char* ga = A + (size_t)(m0 + rb + srow) * D_K + kt * BKB + scolB;
                __builtin_amdgcn_global_load_lds(
                    (const __attribute__((address_space(1))) void*)ga,
                    (__attribute__((address_space(3))) void*)&As[rb * BKB], 16, 0, 0);
            }
#pragma unroll
            for (int u = 0; u < 8; ++u) {    // B: 256 rows = 8 chunks/wave
                int rb = wave * 64 + u * 8;
                int rn = n0 + rb + srow;
                rn = rn < C_N ? rn : C_N - 1;
                const char* gb = wq + (size_t)rn * D_K + kt * BKB + scolB;
                __builtin_amdgcn_global_load_lds(
                    (const __attribute__((address_space(1))) void*)gb,
                    (__attribute__((address_space(3))) void*)&Bs[rb * BKB], 16, 0, 0);
            }
            __syncthreads();

#pragma unroll
            for (int kk = 0; kk < 2; ++kk) {
                // physical slot = logical slot (kk*4+hi) XOR (row&7); row&7 == cl&7
                int px = (((kk << 2) | hi) ^ (cl & 7)) * 16;
                i32x4 af[4], bfr[8];
#pragma unroll
                for (int mi = 0; mi < 4; ++mi)
                    af[mi] = *(const i32x4*)&As[(wm * 64 + mi * 16 + cl) * BKB + px];
#pragma unroll
                for (int ni = 0; ni < 8; ++ni)
                    bfr[ni] = *(const i32x4*)&Bs[(wn * 128 + ni * 16 + cl) * BKB + px];
#pragma unroll
                for (int mi = 0; mi < 4; ++mi)
#pragma unroll
                    for (int ni = 0; ni < 8; ++ni)
                        acc[mi][ni] = __builtin_amdgcn_mfma_i32_16x16x64_i8(af[mi], bfr[ni], acc[mi][ni], 0, 0, 0);
            }
            __syncthreads();
        }

        // epilogue: logit(base-2) = acc * sx_row*KQ2 * sw_col; sum exp2(y - 64*log2e)
        float fcv[8];
        bool cok[8];
#pragma unroll
        for (int ni = 0; ni < 8; ++ni) {
            fcv[ni] = swl[wn * 128 + ni * 16 + cl];
            cok[ni] = (n0 + wn * 128 + ni * 16 + cl) < C_N;
        }
#pragma unroll
        for (int mi = 0; mi < 4; ++mi) {
#pragma unroll
            for (int jj = 0; jj < 4; ++jj) {
                float fr = sxl[wm * 64 + mi * 16 + hi * 4 + jj] * KQ2;
                float se = 0.0f;
#pragma unroll
                for (int ni = 0; ni < 8; ++ni)
                    if (cok[ni]) se += exp2f((float)acc[mi][ni][jj] * fr * fcv[ni] - MAXL2);
#pragma unroll
                for (int xm = 1; xm < 16; xm <<= 1) se += __shfl_xor(se, xm);
                if (cl == 0) rs[wn][wm * 64 + mi * 16 + hi * 4 + jj] = se;
            }
        }
        __syncthreads();
        if (tid < BM) {
            float s = rs[0][tid] + rs[1][tid];
            atomicAdd(&rowsum[m0 + tid], s);
        }
        __syncthreads();   // protect As/Bs/swl/rs before next tile
    }
}

// ------------- kernel C: merged row-finalize + disc reduce + scalar output -------------
__global__ void rowfin_final_kernel(const float* __restrict__ rowsum,
                                    const float* __restrict__ tlogit,
                                    const float* __restrict__ dpart,
                                    float* __restrict__ out) {
    __shared__ float redn[16];
    __shared__ float redd[16];
    int tid = threadIdx.x;          // == row, 0..1023
    float lse = MAXL + logf(rowsum[tid]);
    float st = tlogit[tid];
    // replace exp(st) by exp(st - 64*margin) inside the lse
    float corr = __expf(st - lse) * (__expf(-SCALE_F * MARGIN_F) - 1.0f);
    float lse2 = lse + log1pf(corr);
    float nll = lse2 - (st - SCALE_F * MARGIN_F);
    float dv = dpart[tid];
#pragma unroll
    for (int xm = 1; xm < 64; xm <<= 1) {
        nll += __shfl_xor(nll, xm);
        dv += __shfl_xor(dv, xm);
    }
    if ((tid & 63) == 0) {
        redn[tid >> 6] = nll;
        redd[tid >> 6] = dv;
    }
    __syncthreads();
    if (tid == 0) {
        float sn = 0.0f, sd = 0.0f;
#pragma unroll
        for (int i = 0; i < 16; ++i) { sn += redn[i]; sd += redd[i]; }
        float logp = sn * (1.0f / B_N);
        float disc = sd * (1.0f / B_N);
        float p = __expf(-logp);
        float om = 1.0f - p;
        out[0] = 0.4f * disc + om * om * logp;
    }
}

extern "C" void kernel_launch(void* const* d_in, const int* in_sizes, int n_in,
                              void* d_out, int out_size, void* d_ws, size_t ws_size,
                              hipStream_t stream) {
    const float* x = (const float*)d_in[0];
    const int* target = (const int*)d_in[1];
    const float* ida = (const float*)d_in[2];
    const float* bmat = (const float*)d_in[3];
    float* out = (float*)d_out;

    char* ws = (char*)d_ws;
    size_t off = 0;
    float* rowsum = (float*)(ws + off);  off += (size_t)B_N * 4;         // 4 KB
    char* xq = (char*)(ws + off);        off += (size_t)B_N * D_K;       // 0.5 MB
    char* wq = (char*)(ws + off);        off += (size_t)C_N * D_K;       // 51.2 MB
    float* sx = (float*)(ws + off);      off += (size_t)B_N * 4;
    float* sw = (float*)(ws + off);      off += (size_t)C_N * 4;         // 0.4 MB
    float* tlogit = (float*)(ws + off);  off += (size_t)B_N * 4;
    float* dpart = (float*)(ws + off);   off += (size_t)B_N * 4;
    int* flags = (int*)(ws + off);       off += (size_t)NGRP * 4;

    normx_disc_kernel<<<B_N / 4, 256, 0, stream>>>(x, target, ida, bmat, xq, sx, dpart,
                                                   tlogit, rowsum, flags);
    fused_gemm_kernel<<<GRID, 256, 0, stream>>>(xq, ida, sx, wq, sw, flags, rowsum);
    rowfin_final_kernel<<<1, 1024, 0, stream>>>(rowsum, tlogit, dpart, out);
}

// Round 13
// 219.939 us; speedup vs baseline: 1.1140x; 1.1140x over previous
//
#include <hip/hip_runtime.h>
#include <hip/hip_bf16.h>

typedef __attribute__((ext_vector_type(4))) int i32x4;

#define B_N 1024
#define D_K 512
#define C_N 100000
#define SCALE_F 64.0f
#define MARGIN_F 0.35f
#define BM 128
#define BN 256
#define BKB 128      // K-tile in BYTES per row (= 128 i8 elements)
#define NT_ 391      // ceil(100000/256)
#define MT_ 8        // 1024/128
#define MAXL 64.0f   // global logit bound: |cos|*64 <= 64 (+quant eps, harmless)
#define LOG2E 1.4426950408889634f
#define KQ2 (SCALE_F / (127.0f * 127.0f) * LOG2E)   // base-2 logit scale
#define MAXL2 (MAXL * LOG2E)

__device__ __forceinline__ float dot4(float4 a, float4 b) {
    return a.x * b.x + a.y * b.y + a.z * b.z + a.w * b.w;
}
__device__ __forceinline__ float amax4(float4 a) {
    return fmaxf(fmaxf(fabsf(a.x), fabsf(a.y)), fmaxf(fabsf(a.z), fabsf(a.w)));
}
__device__ __forceinline__ int packq(float v0, float v1, float v2, float v3, float qs) {
    int q0 = __float2int_rn(v0 * qs), q1 = __float2int_rn(v1 * qs);
    int q2 = __float2int_rn(v2 * qs), q3 = __float2int_rn(v3 * qs);
    return (q0 & 0xFF) | ((q1 & 0xFF) << 8) | ((q2 & 0xFF) << 16) | ((q3 & 0xFF) << 24);
}

// ------- kernel A: fused norm_x -> i8 quantize + disc loss + target logit + rowsum zero -------
__global__ void normx_disc_kernel(const float* __restrict__ x,
                                  const int* __restrict__ target,
                                  const float* __restrict__ ida,
                                  const float* __restrict__ bmat,
                                  char* __restrict__ xq,
                                  float* __restrict__ sx,
                                  float* __restrict__ dpart,
                                  float* __restrict__ tlogit,
                                  float* __restrict__ rowsum) {
    int row = blockIdx.x * 4 + (threadIdx.x >> 6);
    int l = threadIdx.x & 63;
    long t = (long)target[row];
    const float4* xp = (const float4*)(x + (size_t)row * D_K);
    const float4* wp = (const float4*)(ida + (size_t)t * D_K);
    const float4* bp = (const float4*)(bmat + (size_t)t * D_K);
    float4 x0 = xp[l], x1 = xp[64 + l];
    float4 w0 = wp[l], w1 = wp[64 + l];
    float4 b0 = bp[l], b1 = bp[64 + l];
    float xssq = dot4(x0, x0) + dot4(x1, x1);
    float wssq = dot4(w0, w0) + dot4(w1, w1);
    float bssq = dot4(b0, b0) + dot4(b1, b1);
    float xmx = fmaxf(amax4(x0), amax4(x1));
#pragma unroll
    for (int m = 1; m < 64; m <<= 1) {
        xssq += __shfl_xor(xssq, m);
        wssq += __shfl_xor(wssq, m);
        bssq += __shfl_xor(bssq, m);
        xmx = fmaxf(xmx, __shfl_xor(xmx, m));
    }
    float xinv = 1.0f / fmaxf(sqrtf(xssq), 1e-12f);
    float winv = 1.0f / fmaxf(sqrtf(wssq), 1e-12f);
    float btn = sqrtf(bssq);
    float cs = fminf(btn, 0.05f) / fmaxf(btn, 1e-12f);

    // quantize normalized x to i8 with per-row scale sxm = max|x_n|
    float sxm = fmaxf(xmx * xinv, 1e-12f);
    float qs = 127.0f / sxm * xinv;     // applied to RAW x
    int* oq = (int*)(xq + (size_t)row * D_K);
    oq[l] = packq(x0.x, x0.y, x0.z, x0.w, qs);
    oq[64 + l] = packq(x1.x, x1.y, x1.z, x1.w, qs);

    float xs[8] = {x0.x, x0.y, x0.z, x0.w, x1.x, x1.y, x1.z, x1.w};
    float wv[8] = {w0.x, w0.y, w0.z, w0.w, w1.x, w1.y, w1.z, w1.w};
    float bv[8] = {b0.x, b0.y, b0.z, b0.w, b1.x, b1.y, b1.z, b1.w};
    float rss = 0.0f, dt = 0.0f;
#pragma unroll
    for (int i = 0; i < 8; ++i) {
        float xn = xs[i] * xinv;
        float wn = wv[i] * winv;
        float d = xn - wn;
        float r = d - bv[i] * cs;
        rss += r * r;
        dt += xn * wn;
    }
#pragma unroll
    for (int m = 1; m < 64; m <<= 1) {
        rss += __shfl_xor(rss, m);
        dt += __shfl_xor(dt, m);
    }
    if (l == 0) {
        sx[row] = sxm;
        dpart[row] = sqrtf(rss);
        tlogit[row] = SCALE_F * dt;
        rowsum[row] = 0.0f;     // zero before gemm's atomics (stream-ordered)
    }
}

// ---------------- kernel B: normalize id_agent rows -> i8 + per-row scale ----------------
__global__ void norm_w_kernel(const float* __restrict__ w,
                              char* __restrict__ wq,
                              float* __restrict__ sw) {
    int row = blockIdx.x * 4 + (threadIdx.x >> 6);
    int l = threadIdx.x & 63;
    const float4* rp = (const float4*)(w + (size_t)row * D_K);
    float4 a = rp[l], b = rp[64 + l];
    float ssq = dot4(a, a) + dot4(b, b);
    float mx = fmaxf(amax4(a), amax4(b));
#pragma unroll
    for (int m = 1; m < 64; m <<= 1) {
        ssq += __shfl_xor(ssq, m);
        mx = fmaxf(mx, __shfl_xor(mx, m));
    }
    float inv = 1.0f / fmaxf(sqrtf(ssq), 1e-12f);
    float swm = fmaxf(mx * inv, 1e-12f);
    float qs = 127.0f / swm * inv;      // applied to RAW w
    int* oq = (int*)(wq + (size_t)row * D_K);
    oq[l] = packq(a.x, a.y, a.z, a.w, qs);
    oq[64 + l] = packq(b.x, b.y, b.z, b.w, qs);
    if (l == 0) sw[row] = swm;
}

// ------------- kernel C: i8 MFMA GEMM (16x16x64_i8), wave-tile 64x128 (acc 4x8),
//               XCD-swizzled, XOR-swizzled LDS, fixed-max sumexp epilogue -------------
// R11 structure; (256,3) requests 3 waves/EU -> 3 blocks/CU (LDS 3x51.7=155KB fits),
// unified reg budget 170/wave: acc 128 + frags 12 + addressing ~= 160.
__global__ __launch_bounds__(256, 3) void gemm_lse_kernel(const char* __restrict__ A,
                                                          const char* __restrict__ W,
                                                          const float* __restrict__ sx,
                                                          const float* __restrict__ sw,
                                                          float* __restrict__ rowsum) {
    __shared__ char As[BM * BKB];   // 16 KB
    __shared__ char Bs[BN * BKB];   // 32 KB
    __shared__ float sxl[BM];
    __shared__ float swl[BN];
    __shared__ float rs[2][BM];

    int tid = threadIdx.x;
    int wave = tid >> 6, l = tid & 63;
    int wm = wave >> 1, wn = wave & 1;   // 2 M-waves x 2 N-waves, wave-tile 64x128

    // XCD-bijective swizzle: 3128 blocks = 8 * 391 exactly; xcd gets a contiguous
    // chunk of tile-space ordered (nt major, mt minor).
    int wgid = (blockIdx.x & 7) * NT_ + (blockIdx.x >> 3);
    int nt = wgid >> 3, mt = wgid & 7;
    int m0 = mt * BM, n0 = nt * BN;

    int srow = l >> 3;                       // row 0..7 within an 8-row staging chunk
    int scolB = ((l & 7) ^ (l >> 3)) * 16;   // pre-swizzled source byte slot (rule #21)

    // per-block scale tiles (ordered by the first __syncthreads below)
    {
        int c = n0 + tid;
        swl[tid] = (c < C_N) ? sw[c] : 0.0f;   // 0 => exp2(-92) contribution, negligible
        if (tid < BM) sxl[tid] = sx[m0 + tid];
    }

    i32x4 acc[4][8];
#pragma unroll
    for (int i = 0; i < 4; ++i)
#pragma unroll
        for (int j = 0; j < 8; ++j) acc[i][j] = (i32x4){0, 0, 0, 0};

    int cl = l & 15, hi = l >> 4;

    for (int kt = 0; kt < 4; ++kt) {         // 4 K-tiles of 128 i8
#pragma unroll
        for (int i = 0; i < 4; ++i) {        // A: 128 rows = 4 chunks/wave
            int rb = wave * 32 + i * 8;
            const char* ga = A + (size_t)(m0 + rb + srow) * D_K + kt * BKB + scolB;
            __builtin_amdgcn_global_load_lds(
                (const __attribute__((address_space(1))) void*)ga,
                (__attribute__((address_space(3))) void*)&As[rb * BKB], 16, 0, 0);
        }
#pragma unroll
        for (int i = 0; i < 8; ++i) {        // B: 256 rows = 8 chunks/wave
            int rb = wave * 64 + i * 8;
            int rn = n0 + rb + srow;
            rn = rn < C_N ? rn : C_N - 1;
            const char* gb = W + (size_t)rn * D_K + kt * BKB + scolB;
            __builtin_amdgcn_global_load_lds(
                (const __attribute__((address_space(1))) void*)gb,
                (__attribute__((address_space(3))) void*)&Bs[rb * BKB], 16, 0, 0);
        }
        __syncthreads();

#pragma unroll
        for (int kk = 0; kk < 2; ++kk) {
            // physical slot = logical slot (kk*4+hi) XOR (row&7); row&7 == cl&7
            int px = (((kk << 2) | hi) ^ (cl & 7)) * 16;
            i32x4 af[4], bfr[8];
#pragma unroll
            for (int mi = 0; mi < 4; ++mi)
                af[mi] = *(const i32x4*)&As[(wm * 64 + mi * 16 + cl) * BKB + px];
#pragma unroll
            for (int ni = 0; ni < 8; ++ni)
                bfr[ni] = *(const i32x4*)&Bs[(wn * 128 + ni * 16 + cl) * BKB + px];
#pragma unroll
            for (int mi = 0; mi < 4; ++mi)
#pragma unroll
                for (int ni = 0; ni < 8; ++ni)
                    acc[mi][ni] = __builtin_amdgcn_mfma_i32_16x16x64_i8(af[mi], bfr[ni], acc[mi][ni], 0, 0, 0);
        }
        __syncthreads();
    }

    // epilogue: base-2 logit = acc * (sx_row*KQ2) * sw_col; per-row sum exp2(y - 64*log2e)
    float fcv[8];
#pragma unroll
    for (int ni = 0; ni < 8; ++ni)
        fcv[ni] = swl[wn * 128 + ni * 16 + cl];

#pragma unroll
    for (int mi = 0; mi < 4; ++mi) {
#pragma unroll
        for (int j = 0; j < 4; ++j) {
            float fr = sxl[wm * 64 + mi * 16 + hi * 4 + j] * KQ2;
            float se = 0.0f;
#pragma unroll
            for (int ni = 0; ni < 8; ++ni)
                se += exp2f((float)acc[mi][ni][j] * fr * fcv[ni] - MAXL2);
#pragma unroll
            for (int xm = 1; xm < 16; xm <<= 1) se += __shfl_xor(se, xm);
            if (cl == 0) rs[wn][wm * 64 + mi * 16 + hi * 4 + j] = se;
        }
    }
    __syncthreads();
    if (tid < BM) {
        float s = rs[0][tid] + rs[1][tid];
        atomicAdd(&rowsum[m0 + tid], s);
    }
}

// ------------- kernel D: merged row-finalize + disc reduce + scalar output -------------
__global__ void rowfin_final_kernel(const float* __restrict__ rowsum,
                                    const float* __restrict__ tlogit,
                                    const float* __restrict__ dpart,
                                    float* __restrict__ out) {
    __shared__ float redn[16];
    __shared__ float redd[16];
    int tid = threadIdx.x;          // == row, 0..1023
    float lse = MAXL + logf(rowsum[tid]);
    float st = tlogit[tid];
    // replace exp(st) by exp(st - 64*margin) inside the lse
    float corr = __expf(st - lse) * (__expf(-SCALE_F * MARGIN_F) - 1.0f);
    float lse2 = lse + log1pf(corr);
    float nll = lse2 - (st - SCALE_F * MARGIN_F);
    float dv = dpart[tid];
#pragma unroll
    for (int xm = 1; xm < 64; xm <<= 1) {
        nll += __shfl_xor(nll, xm);
        dv += __shfl_xor(dv, xm);
    }
    if ((tid & 63) == 0) {
        redn[tid >> 6] = nll;
        redd[tid >> 6] = dv;
    }
    __syncthreads();
    if (tid == 0) {
        float sn = 0.0f, sd = 0.0f;
#pragma unroll
        for (int i = 0; i < 16; ++i) { sn += redn[i]; sd += redd[i]; }
        float logp = sn * (1.0f / B_N);
        float disc = sd * (1.0f / B_N);
        float p = __expf(-logp);
        float om = 1.0f - p;
        out[0] = 0.4f * disc + om * om * logp;
    }
}

extern "C" void kernel_launch(void* const* d_in, const int* in_sizes, int n_in,
                              void* d_out, int out_size, void* d_ws, size_t ws_size,
                              hipStream_t stream) {
    const float* x = (const float*)d_in[0];
    const int* target = (const int*)d_in[1];
    const float* ida = (const float*)d_in[2];
    const float* bmat = (const float*)d_in[3];
    float* out = (float*)d_out;

    char* ws = (char*)d_ws;
    size_t off = 0;
    float* rowsum = (float*)(ws + off);  off += (size_t)B_N * 4;         // 4 KB
    char* xq = (char*)(ws + off);        off += (size_t)B_N * D_K;       // 0.5 MB
    char* wq = (char*)(ws + off);        off += (size_t)C_N * D_K;       // 51.2 MB
    float* sx = (float*)(ws + off);      off += (size_t)B_N * 4;
    float* sw = (float*)(ws + off);      off += (size_t)C_N * 4;         // 0.4 MB
    float* tlogit = (float*)(ws + off);  off += (size_t)B_N * 4;
    float* dpart = (float*)(ws + off);   off += (size_t)B_N * 4;

    normx_disc_kernel<<<B_N / 4, 256, 0, stream>>>(x, target, ida, bmat, xq, sx, dpart, tlogit, rowsum);
    norm_w_kernel<<<C_N / 4, 256, 0, stream>>>(ida, wq, sw);
    gemm_lse_kernel<<<MT_ * NT_, 256, 0, stream>>>(xq, wq, sx, sw, rowsum);
    rowfin_final_kernel<<<1, 1024, 0, stream>>>(rowsum, tlogit, dpart, out);
}

// Round 14
// 134.584 us; speedup vs baseline: 1.8205x; 1.6342x over previous
//
#include <hip/hip_runtime.h>
#include <hip/hip_bf16.h>

typedef __attribute__((ext_vector_type(4))) int i32x4;

#define B_N 1024
#define D_K 512
#define C_N 100000
#define SCALE_F 64.0f
#define MARGIN_F 0.35f
#define BM 128
#define BN 256
#define BKB 128      // K-tile in BYTES per row (= 128 i8 elements)
#define NT_ 391      // ceil(100000/256)
#define MT_ 8        // 1024/128
#define WBLKS 25000  // norm_w blocks (4 rows each) in the merged prep kernel
#define MAXL 64.0f   // global logit bound: |cos|*64 <= 64 (+quant eps, harmless)
#define LOG2E 1.4426950408889634f
#define KQ2 (SCALE_F / (127.0f * 127.0f) * LOG2E)   // base-2 logit scale
#define MAXL2 (MAXL * LOG2E)

__device__ __forceinline__ float dot4(float4 a, float4 b) {
    return a.x * b.x + a.y * b.y + a.z * b.z + a.w * b.w;
}
__device__ __forceinline__ float amax4(float4 a) {
    return fmaxf(fmaxf(fabsf(a.x), fabsf(a.y)), fmaxf(fabsf(a.z), fabsf(a.w)));
}
__device__ __forceinline__ int packq(float v0, float v1, float v2, float v3, float qs) {
    int q0 = __float2int_rn(v0 * qs), q1 = __float2int_rn(v1 * qs);
    int q2 = __float2int_rn(v2 * qs), q3 = __float2int_rn(v3 * qs);
    return (q0 & 0xFF) | ((q1 & 0xFF) << 8) | ((q2 & 0xFF) << 16) | ((q3 & 0xFF) << 24);
}

// ------- kernel A (merged prep): blocks [0,25000) quantize W rows; blocks
//         [25000,25256) do norm_x->i8 + disc loss + target logit + rowsum zero -------
__global__ void prep_kernel(const float* __restrict__ x,
                            const int* __restrict__ target,
                            const float* __restrict__ ida,
                            const float* __restrict__ bmat,
                            char* __restrict__ xq,
                            float* __restrict__ sx,
                            char* __restrict__ wq,
                            float* __restrict__ sw,
                            float* __restrict__ dpart,
                            float* __restrict__ tlogit,
                            float* __restrict__ rowsum) {
    int blk = blockIdx.x;
    int wave = threadIdx.x >> 6;
    int l = threadIdx.x & 63;

    if (blk < WBLKS) {
        // ---- W path: normalize + i8 quantize one row per wave ----
        int row = blk * 4 + wave;
        const float4* rp = (const float4*)(ida + (size_t)row * D_K);
        float4 a = rp[l], b = rp[64 + l];
        float ssq = dot4(a, a) + dot4(b, b);
        float mx = fmaxf(amax4(a), amax4(b));
#pragma unroll
        for (int m = 1; m < 64; m <<= 1) {
            ssq += __shfl_xor(ssq, m);
            mx = fmaxf(mx, __shfl_xor(mx, m));
        }
        float inv = 1.0f / fmaxf(sqrtf(ssq), 1e-12f);
        float swm = fmaxf(mx * inv, 1e-12f);
        float qs = 127.0f / swm * inv;      // applied to RAW w
        int* oq = (int*)(wq + (size_t)row * D_K);
        oq[l] = packq(a.x, a.y, a.z, a.w, qs);
        oq[64 + l] = packq(b.x, b.y, b.z, b.w, qs);
        if (l == 0) sw[row] = swm;
        return;
    }

    // ---- x path: norm_x -> i8, disc loss, exact target logit, rowsum zero ----
    int row = (blk - WBLKS) * 4 + wave;
    long t = (long)target[row];
    const float4* xp = (const float4*)(x + (size_t)row * D_K);
    const float4* wp = (const float4*)(ida + (size_t)t * D_K);
    const float4* bp = (const float4*)(bmat + (size_t)t * D_K);
    float4 x0 = xp[l], x1 = xp[64 + l];
    float4 w0 = wp[l], w1 = wp[64 + l];
    float4 b0 = bp[l], b1 = bp[64 + l];
    float xssq = dot4(x0, x0) + dot4(x1, x1);
    float wssq = dot4(w0, w0) + dot4(w1, w1);
    float bssq = dot4(b0, b0) + dot4(b1, b1);
    float xmx = fmaxf(amax4(x0), amax4(x1));
#pragma unroll
    for (int m = 1; m < 64; m <<= 1) {
        xssq += __shfl_xor(xssq, m);
        wssq += __shfl_xor(wssq, m);
        bssq += __shfl_xor(bssq, m);
        xmx = fmaxf(xmx, __shfl_xor(xmx, m));
    }
    float xinv = 1.0f / fmaxf(sqrtf(xssq), 1e-12f);
    float winv = 1.0f / fmaxf(sqrtf(wssq), 1e-12f);
    float btn = sqrtf(bssq);
    float cs = fminf(btn, 0.05f) / fmaxf(btn, 1e-12f);

    // quantize normalized x to i8 with per-row scale sxm = max|x_n|
    float sxm = fmaxf(xmx * xinv, 1e-12f);
    float qs = 127.0f / sxm * xinv;     // applied to RAW x
    int* oq = (int*)(xq + (size_t)row * D_K);
    oq[l] = packq(x0.x, x0.y, x0.z, x0.w, qs);
    oq[64 + l] = packq(x1.x, x1.y, x1.z, x1.w, qs);

    float xs[8] = {x0.x, x0.y, x0.z, x0.w, x1.x, x1.y, x1.z, x1.w};
    float wv[8] = {w0.x, w0.y, w0.z, w0.w, w1.x, w1.y, w1.z, w1.w};
    float bv[8] = {b0.x, b0.y, b0.z, b0.w, b1.x, b1.y, b1.z, b1.w};
    float rss = 0.0f, dt = 0.0f;
#pragma unroll
    for (int i = 0; i < 8; ++i) {
        float xn = xs[i] * xinv;
        float wn = wv[i] * winv;
        float d = xn - wn;
        float r = d - bv[i] * cs;
        rss += r * r;
        dt += xn * wn;
    }
#pragma unroll
    for (int m = 1; m < 64; m <<= 1) {
        rss += __shfl_xor(rss, m);
        dt += __shfl_xor(dt, m);
    }
    if (l == 0) {
        sx[row] = sxm;
        dpart[row] = sqrtf(rss);
        tlogit[row] = SCALE_F * dt;
        rowsum[row] = 0.0f;     // zero before gemm's atomics (stream-ordered)
    }
}

// ------------- kernel B: i8 MFMA GEMM (16x16x64_i8), wave-tile 64x128 (acc 4x8),
//               XCD-swizzled, XOR-swizzled LDS, fixed-max base-2 sumexp epilogue -------------
// Exact R11 structure at (256,2); staging bases hoisted, kt loop unrolled,
// exp2 epilogue with log2e folded into the row scale, branchless OOB (sw=0).
__global__ __launch_bounds__(256, 2) void gemm_lse_kernel(const char* __restrict__ A,
                                                          const char* __restrict__ W,
                                                          const float* __restrict__ sx,
                                                          const float* __restrict__ sw,
                                                          float* __restrict__ rowsum) {
    __shared__ char As[BM * BKB];   // 16 KB
    __shared__ char Bs[BN * BKB];   // 32 KB
    __shared__ float sxl[BM];
    __shared__ float swl[BN];
    __shared__ float rs[2][BM];

    int tid = threadIdx.x;
    int wave = tid >> 6, l = tid & 63;
    int wm = wave >> 1, wn = wave & 1;   // 2 M-waves x 2 N-waves, wave-tile 64x128

    // XCD-bijective swizzle: 3128 blocks = 8 * 391 exactly; xcd gets a contiguous
    // chunk of tile-space ordered (nt major, mt minor).
    int wgid = (blockIdx.x & 7) * NT_ + (blockIdx.x >> 3);
    int nt = wgid >> 3, mt = wgid & 7;
    int m0 = mt * BM, n0 = nt * BN;

    int srow = l >> 3;                       // row 0..7 within an 8-row staging chunk
    int scolB = ((l & 7) ^ (l >> 3)) * 16;   // pre-swizzled source byte slot (rule #21)

    // per-block scale tiles (ordered by the first __syncthreads below)
    {
        int c = n0 + tid;
        swl[tid] = (c < C_N) ? sw[c] : 0.0f;   // 0 => 2^-92 contribution, negligible
        if (tid < BM) sxl[tid] = sx[m0 + tid];
    }

    // hoisted staging base pointers (constant across the unrolled kt loop)
    const char* aBase = A + (size_t)(m0 + wave * 32 + srow) * D_K + scolB;
    const char* bBase[8];
#pragma unroll
    for (int i = 0; i < 8; ++i) {
        int rn = n0 + wave * 64 + i * 8 + srow;
        rn = rn < C_N ? rn : C_N - 1;
        bBase[i] = W + (size_t)rn * D_K + scolB;
    }

    i32x4 acc[4][8];
#pragma unroll
    for (int i = 0; i < 4; ++i)
#pragma unroll
        for (int j = 0; j < 8; ++j) acc[i][j] = (i32x4){0, 0, 0, 0};

    int cl = l & 15, hi = l >> 4;

#pragma unroll
    for (int kt = 0; kt < 4; ++kt) {         // 4 K-tiles of 128 i8 (fully unrolled)
#pragma unroll
        for (int i = 0; i < 4; ++i)          // A: 128 rows = 4 chunks/wave
            __builtin_amdgcn_global_load_lds(
                (const __attribute__((address_space(1))) void*)(aBase + i * (8 * D_K) + kt * BKB),
                (__attribute__((address_space(3))) void*)&As[(wave * 32 + i * 8) * BKB], 16, 0, 0);
#pragma unroll
        for (int i = 0; i < 8; ++i)          // B: 256 rows = 8 chunks/wave
            __builtin_amdgcn_global_load_lds(
                (const __attribute__((address_space(1))) void*)(bBase[i] + kt * BKB),
                (__attribute__((address_space(3))) void*)&Bs[(wave * 64 + i * 8) * BKB], 16, 0, 0);
        __syncthreads();

#pragma unroll
        for (int kk = 0; kk < 2; ++kk) {
            // physical slot = logical slot (kk*4+hi) XOR (row&7); row&7 == cl&7
            int px = (((kk << 2) | hi) ^ (cl & 7)) * 16;
            i32x4 af[4], bfr[8];
#pragma unroll
            for (int mi = 0; mi < 4; ++mi)
                af[mi] = *(const i32x4*)&As[(wm * 64 + mi * 16 + cl) * BKB + px];
#pragma unroll
            for (int ni = 0; ni < 8; ++ni)
                bfr[ni] = *(const i32x4*)&Bs[(wn * 128 + ni * 16 + cl) * BKB + px];
#pragma unroll
            for (int mi = 0; mi < 4; ++mi)
#pragma unroll
                for (int ni = 0; ni < 8; ++ni)
                    acc[mi][ni] = __builtin_amdgcn_mfma_i32_16x16x64_i8(af[mi], bfr[ni], acc[mi][ni], 0, 0, 0);
        }
        __syncthreads();
    }

    // epilogue: base-2 logit = acc * (sx_row*KQ2) * sw_col; per-row sum exp2(y - 64*log2e)
    float fcv[8];
#pragma unroll
    for (int ni = 0; ni < 8; ++ni)
        fcv[ni] = swl[wn * 128 + ni * 16 + cl];

#pragma unroll
    for (int mi = 0; mi < 4; ++mi) {
#pragma unroll
        for (int j = 0; j < 4; ++j) {
            float fr = sxl[wm * 64 + mi * 16 + hi * 4 + j] * KQ2;
            float se = 0.0f;
#pragma unroll
            for (int ni = 0; ni < 8; ++ni)
                se += exp2f((float)acc[mi][ni][j] * fr * fcv[ni] - MAXL2);
#pragma unroll
            for (int xm = 1; xm < 16; xm <<= 1) se += __shfl_xor(se, xm);
            if (cl == 0) rs[wn][wm * 64 + mi * 16 + hi * 4 + j] = se;
        }
    }
    __syncthreads();
    if (tid < BM) {
        float s = rs[0][tid] + rs[1][tid];
        atomicAdd(&rowsum[m0 + tid], s);
    }
}

// ------------- kernel C: merged row-finalize + disc reduce + scalar output -------------
__global__ void rowfin_final_kernel(const float* __restrict__ rowsum,
                                    const float* __restrict__ tlogit,
                                    const float* __restrict__ dpart,
                                    float* __restrict__ out) {
    __shared__ float redn[16];
    __shared__ float redd[16];
    int tid = threadIdx.x;          // == row, 0..1023
    float lse = MAXL + logf(rowsum[tid]);
    float st = tlogit[tid];
    // replace exp(st) by exp(st - 64*margin) inside the lse
    float corr = __expf(st - lse) * (__expf(-SCALE_F * MARGIN_F) - 1.0f);
    float lse2 = lse + log1pf(corr);
    float nll = lse2 - (st - SCALE_F * MARGIN_F);
    float dv = dpart[tid];
#pragma unroll
    for (int xm = 1; xm < 64; xm <<= 1) {
        nll += __shfl_xor(nll, xm);
        dv += __shfl_xor(dv, xm);
    }
    if ((tid & 63) == 0) {
        redn[tid >> 6] = nll;
        redd[tid >> 6] = dv;
    }
    __syncthreads();
    if (tid == 0) {
        float sn = 0.0f, sd = 0.0f;
#pragma unroll
        for (int i = 0; i < 16; ++i) { sn += redn[i]; sd += redd[i]; }
        float logp = sn * (1.0f / B_N);
        float disc = sd * (1.0f / B_N);
        float p = __expf(-logp);
        float om = 1.0f - p;
        out[0] = 0.4f * disc + om * om * logp;
    }
}

extern "C" void kernel_launch(void* const* d_in, const int* in_sizes, int n_in,
                              void* d_out, int out_size, void* d_ws, size_t ws_size,
                              hipStream_t stream) {
    const float* x = (const float*)d_in[0];
    const int* target = (const int*)d_in[1];
    const float* ida = (const float*)d_in[2];
    const float* bmat = (const float*)d_in[3];
    float* out = (float*)d_out;

    char* ws = (char*)d_ws;
    size_t off = 0;
    float* rowsum = (float*)(ws + off);  off += (size_t)B_N * 4;         // 4 KB
    char* xq = (char*)(ws + off);        off += (size_t)B_N * D_K;       // 0.5 MB
    char* wq = (char*)(ws + off);        off += (size_t)C_N * D_K;       // 51.2 MB
    float* sx = (float*)(ws + off);      off += (size_t)B_N * 4;
    float* sw = (float*)(ws + off);      off += (size_t)C_N * 4;         // 0.4 MB
    float* tlogit = (float*)(ws + off);  off += (size_t)B_N * 4;
    float* dpart = (float*)(ws + off);   off += (size_t)B_N * 4;

    prep_kernel<<<WBLKS + B_N / 4, 256, 0, stream>>>(x, target, ida, bmat, xq, sx,
                                                     wq, sw, dpart, tlogit, rowsum);
    gemm_lse_kernel<<<MT_ * NT_, 256, 0, stream>>>(xq, wq, sx, sw, rowsum);
    rowfin_final_kernel<<<1, 1024, 0, stream>>>(rowsum, tlogit, dpart, out);
}

// Round 15
// 134.446 us; speedup vs baseline: 1.8224x; 1.0010x over previous
//
#include <hip/hip_runtime.h>
#include <hip/hip_bf16.h>

typedef __attribute__((ext_vector_type(4))) int i32x4;

#define B_N 1024
#define D_K 512
#define C_N 100000
#define SCALE_F 64.0f
#define MARGIN_F 0.35f
#define BM 128
#define BN 256
#define BKB 128      // K-tile in BYTES per row (= 128 i8 elements)
#define NT_ 391      // ceil(100000/256)
#define MT_ 8        // 1024/128
#define WBLKS 25000  // norm_w blocks (4 rows each) in the merged prep kernel
#define MAXL 64.0f   // global logit bound: |cos|*64 <= 64 (+quant eps, harmless)
#define LOG2E 1.4426950408889634f
#define KQ2 (SCALE_F / (127.0f * 127.0f) * LOG2E)   // base-2 logit scale
#define MAXL2 (MAXL * LOG2E)

__device__ __forceinline__ float dot4(float4 a, float4 b) {
    return a.x * b.x + a.y * b.y + a.z * b.z + a.w * b.w;
}
__device__ __forceinline__ float amax4(float4 a) {
    return fmaxf(fmaxf(fabsf(a.x), fabsf(a.y)), fmaxf(fabsf(a.z), fabsf(a.w)));
}
__device__ __forceinline__ int packq(float v0, float v1, float v2, float v3, float qs) {
    int q0 = __float2int_rn(v0 * qs), q1 = __float2int_rn(v1 * qs);
    int q2 = __float2int_rn(v2 * qs), q3 = __float2int_rn(v3 * qs);
    return (q0 & 0xFF) | ((q1 & 0xFF) << 8) | ((q2 & 0xFF) << 16) | ((q3 & 0xFF) << 24);
}

// ------- kernel A (merged prep): blocks [0,25000) quantize W rows; blocks
//         [25000,25256) do norm_x->i8 + disc loss + target logit + rowsum zero -------
__global__ void prep_kernel(const float* __restrict__ x,
                            const int* __restrict__ target,
                            const float* __restrict__ ida,
                            const float* __restrict__ bmat,
                            char* __restrict__ xq,
                            float* __restrict__ sx,
                            char* __restrict__ wq,
                            float* __restrict__ sw,
                            float* __restrict__ dpart,
                            float* __restrict__ tlogit,
                            float* __restrict__ rowsum) {
    int blk = blockIdx.x;
    int wave = threadIdx.x >> 6;
    int l = threadIdx.x & 63;

    if (blk < WBLKS) {
        // ---- W path: normalize + i8 quantize one row per wave ----
        int row = blk * 4 + wave;
        const float4* rp = (const float4*)(ida + (size_t)row * D_K);
        float4 a = rp[l], b = rp[64 + l];
        float ssq = dot4(a, a) + dot4(b, b);
        float mx = fmaxf(amax4(a), amax4(b));
#pragma unroll
        for (int m = 1; m < 64; m <<= 1) {
            ssq += __shfl_xor(ssq, m);
            mx = fmaxf(mx, __shfl_xor(mx, m));
        }
        float inv = 1.0f / fmaxf(sqrtf(ssq), 1e-12f);
        float swm = fmaxf(mx * inv, 1e-12f);
        float qs = 127.0f / swm * inv;      // applied to RAW w
        int* oq = (int*)(wq + (size_t)row * D_K);
        oq[l] = packq(a.x, a.y, a.z, a.w, qs);
        oq[64 + l] = packq(b.x, b.y, b.z, b.w, qs);
        if (l == 0) sw[row] = swm;
        return;
    }

    // ---- x path: norm_x -> i8, disc loss, exact target logit, rowsum zero ----
    int row = (blk - WBLKS) * 4 + wave;
    long t = (long)target[row];
    const float4* xp = (const float4*)(x + (size_t)row * D_K);
    const float4* wp = (const float4*)(ida + (size_t)t * D_K);
    const float4* bp = (const float4*)(bmat + (size_t)t * D_K);
    float4 x0 = xp[l], x1 = xp[64 + l];
    float4 w0 = wp[l], w1 = wp[64 + l];
    float4 b0 = bp[l], b1 = bp[64 + l];
    float xssq = dot4(x0, x0) + dot4(x1, x1);
    float wssq = dot4(w0, w0) + dot4(w1, w1);
    float bssq = dot4(b0, b0) + dot4(b1, b1);
    float xmx = fmaxf(amax4(x0), amax4(x1));
#pragma unroll
    for (int m = 1; m < 64; m <<= 1) {
        xssq += __shfl_xor(xssq, m);
        wssq += __shfl_xor(wssq, m);
        bssq += __shfl_xor(bssq, m);
        xmx = fmaxf(xmx, __shfl_xor(xmx, m));
    }
    float xinv = 1.0f / fmaxf(sqrtf(xssq), 1e-12f);
    float winv = 1.0f / fmaxf(sqrtf(wssq), 1e-12f);
    float btn = sqrtf(bssq);
    float cs = fminf(btn, 0.05f) / fmaxf(btn, 1e-12f);

    // quantize normalized x to i8 with per-row scale sxm = max|x_n|
    float sxm = fmaxf(xmx * xinv, 1e-12f);
    float qs = 127.0f / sxm * xinv;     // applied to RAW x
    int* oq = (int*)(xq + (size_t)row * D_K);
    oq[l] = packq(x0.x, x0.y, x0.z, x0.w, qs);
    oq[64 + l] = packq(x1.x, x1.y, x1.z, x1.w, qs);

    float xs[8] = {x0.x, x0.y, x0.z, x0.w, x1.x, x1.y, x1.z, x1.w};
    float wv[8] = {w0.x, w0.y, w0.z, w0.w, w1.x, w1.y, w1.z, w1.w};
    float bv[8] = {b0.x, b0.y, b0.z, b0.w, b1.x, b1.y, b1.z, b1.w};
    float rss = 0.0f, dt = 0.0f;
#pragma unroll
    for (int i = 0; i < 8; ++i) {
        float xn = xs[i] * xinv;
        float wn = wv[i] * winv;
        float d = xn - wn;
        float r = d - bv[i] * cs;
        rss += r * r;
        dt += xn * wn;
    }
#pragma unroll
    for (int m = 1; m < 64; m <<= 1) {
        rss += __shfl_xor(rss, m);
        dt += __shfl_xor(dt, m);
    }
    if (l == 0) {
        sx[row] = sxm;
        dpart[row] = sqrtf(rss);
        tlogit[row] = SCALE_F * dt;
        rowsum[row] = 0.0f;     // zero before gemm's atomics (stream-ordered)
    }
}

// ------------- kernel B: i8 MFMA GEMM (16x16x64_i8), 512 threads / 8 waves,
//               wave-tile 64x64 (acc 4x4), XCD-swizzled, XOR-swizzled LDS,
//               fixed-max base-2 sumexp epilogue -------------
// Same 128x256 block-tile & staging bytes as R14, but 16 waves/CU (4/SIMD):
// block A's staging drain hides under block B's MFMA. acc 64 regs << (512,4)
// cap of 128 -> no spill expected.
__global__ __launch_bounds__(512, 4) void gemm_lse_kernel(const char* __restrict__ A,
                                                          const char* __restrict__ W,
                                                          const float* __restrict__ sx,
                                                          const float* __restrict__ sw,
                                                          float* __restrict__ rowsum) {
    __shared__ char As[BM * BKB];   // 16 KB
    __shared__ char Bs[BN * BKB];   // 32 KB
    __shared__ float sxl[BM];
    __shared__ float swl[BN];
    __shared__ float rs[4][BM];

    int tid = threadIdx.x;
    int wave = tid >> 6, l = tid & 63;
    int wm = wave >> 2, wn = wave & 3;   // 2 M-waves x 4 N-waves, wave-tile 64x64

    // XCD-bijective swizzle: 3128 blocks = 8 * 391 exactly; xcd gets a contiguous
    // chunk of tile-space ordered (nt major, mt minor).
    int wgid = (blockIdx.x & 7) * NT_ + (blockIdx.x >> 3);
    int nt = wgid >> 3, mt = wgid & 7;
    int m0 = mt * BM, n0 = nt * BN;

    int srow = l >> 3;                       // row 0..7 within an 8-row staging chunk
    int scolB = ((l & 7) ^ (l >> 3)) * 16;   // pre-swizzled source byte slot (rule #21)

    // per-block scale tiles (ordered by the first __syncthreads below)
    {
        if (tid < BN) {
            int c = n0 + tid;
            swl[tid] = (c < C_N) ? sw[c] : 0.0f;   // 0 => 2^-92 contribution, negligible
        } else if (tid < BN + BM) {
            sxl[tid - BN] = sx[m0 + tid - BN];
        }
    }

    // hoisted staging base pointers: A 16 chunks -> 2/wave; B 32 chunks -> 4/wave
    const char* aBase = A + (size_t)(m0 + wave * 16 + srow) * D_K + scolB;
    const char* bBase[4];
#pragma unroll
    for (int i = 0; i < 4; ++i) {
        int rn = n0 + wave * 32 + i * 8 + srow;
        rn = rn < C_N ? rn : C_N - 1;
        bBase[i] = W + (size_t)rn * D_K + scolB;
    }

    i32x4 acc[4][4];
#pragma unroll
    for (int i = 0; i < 4; ++i)
#pragma unroll
        for (int j = 0; j < 4; ++j) acc[i][j] = (i32x4){0, 0, 0, 0};

    int cl = l & 15, hi = l >> 4;

#pragma unroll
    for (int kt = 0; kt < 4; ++kt) {         // 4 K-tiles of 128 i8 (fully unrolled)
#pragma unroll
        for (int i = 0; i < 2; ++i)          // A: 128 rows = 2 chunks/wave
            __builtin_amdgcn_global_load_lds(
                (const __attribute__((address_space(1))) void*)(aBase + i * (8 * D_K) + kt * BKB),
                (__attribute__((address_space(3))) void*)&As[(wave * 16 + i * 8) * BKB], 16, 0, 0);
#pragma unroll
        for (int i = 0; i < 4; ++i)          // B: 256 rows = 4 chunks/wave
            __builtin_amdgcn_global_load_lds(
                (const __attribute__((address_space(1))) void*)(bBase[i] + kt * BKB),
                (__attribute__((address_space(3))) void*)&Bs[(wave * 32 + i * 8) * BKB], 16, 0, 0);
        __syncthreads();

#pragma unroll
        for (int kk = 0; kk < 2; ++kk) {
            // physical slot = logical slot (kk*4+hi) XOR (row&7); row&7 == cl&7
            int px = (((kk << 2) | hi) ^ (cl & 7)) * 16;
            i32x4 af[4], bfr[4];
#pragma unroll
            for (int mi = 0; mi < 4; ++mi)
                af[mi] = *(const i32x4*)&As[(wm * 64 + mi * 16 + cl) * BKB + px];
#pragma unroll
            for (int ni = 0; ni < 4; ++ni)
                bfr[ni] = *(const i32x4*)&Bs[(wn * 64 + ni * 16 + cl) * BKB + px];
#pragma unroll
            for (int mi = 0; mi < 4; ++mi)
#pragma unroll
                for (int ni = 0; ni < 4; ++ni)
                    acc[mi][ni] = __builtin_amdgcn_mfma_i32_16x16x64_i8(af[mi], bfr[ni], acc[mi][ni], 0, 0, 0);
        }
        __syncthreads();
    }

    // epilogue: base-2 logit = acc * (sx_row*KQ2) * sw_col; per-row sum exp2(y - 64*log2e)
    float fcv[4];
#pragma unroll
    for (int ni = 0; ni < 4; ++ni)
        fcv[ni] = swl[wn * 64 + ni * 16 + cl];

#pragma unroll
    for (int mi = 0; mi < 4; ++mi) {
#pragma unroll
        for (int j = 0; j < 4; ++j) {
            float fr = sxl[wm * 64 + mi * 16 + hi * 4 + j] * KQ2;
            float se = 0.0f;
#pragma unroll
            for (int ni = 0; ni < 4; ++ni)
                se += exp2f((float)acc[mi][ni][j] * fr * fcv[ni] - MAXL2);
#pragma unroll
            for (int xm = 1; xm < 16; xm <<= 1) se += __shfl_xor(se, xm);
            if (cl == 0) rs[wn][wm * 64 + mi * 16 + hi * 4 + j] = se;
        }
    }
    __syncthreads();
    if (tid < BM) {
        float s = rs[0][tid] + rs[1][tid] + rs[2][tid] + rs[3][tid];
        atomicAdd(&rowsum[m0 + tid], s);
    }
}

// ------------- kernel C: merged row-finalize + disc reduce + scalar output -------------
__global__ void rowfin_final_kernel(const float* __restrict__ rowsum,
                                    const float* __restrict__ tlogit,
                                    const float* __restrict__ dpart,
                                    float* __restrict__ out) {
    __shared__ float redn[16];
    __shared__ float redd[16];
    int tid = threadIdx.x;          // == row, 0..1023
    float lse = MAXL + logf(rowsum[tid]);
    float st = tlogit[tid];
    // replace exp(st) by exp(st - 64*margin) inside the lse
    float corr = __expf(st - lse) * (__expf(-SCALE_F * MARGIN_F) - 1.0f);
    float lse2 = lse + log1pf(corr);
    float nll = lse2 - (st - SCALE_F * MARGIN_F);
    float dv = dpart[tid];
#pragma unroll
    for (int xm = 1; xm < 64; xm <<= 1) {
        nll += __shfl_xor(nll, xm);
        dv += __shfl_xor(dv, xm);
    }
    if ((tid & 63) == 0) {
        redn[tid >> 6] = nll;
        redd[tid >> 6] = dv;
    }
    __syncthreads();
    if (tid == 0) {
        float sn = 0.0f, sd = 0.0f;
#pragma unroll
        for (int i = 0; i < 16; ++i) { sn += redn[i]; sd += redd[i]; }
        float logp = sn * (1.0f / B_N);
        float disc = sd * (1.0f / B_N);
        float p = __expf(-logp);
        float om = 1.0f - p;
        out[0] = 0.4f * disc + om * om * logp;
    }
}

extern "C" void kernel_launch(void* const* d_in, const int* in_sizes, int n_in,
                              void* d_out, int out_size, void* d_ws, size_t ws_size,
                              hipStream_t stream) {
    const float* x = (const float*)d_in[0];
    const int* target = (const int*)d_in[1];
    const float* ida = (const float*)d_in[2];
    const float* bmat = (const float*)d_in[3];
    float* out = (float*)d_out;

    char* ws = (char*)d_ws;
    size_t off = 0;
    float* rowsum = (float*)(ws + off);  off += (size_t)B_N * 4;         // 4 KB
    char* xq = (char*)(ws + off);        off += (size_t)B_N * D_K;       // 0.5 MB
    char* wq = (char*)(ws + off);        off += (size_t)C_N * D_K;       // 51.2 MB
    float* sx = (float*)(ws + off);      off += (size_t)B_N * 4;
    float* sw = (float*)(ws + off);      off += (size_t)C_N * 4;         // 0.4 MB
    float* tlogit = (float*)(ws + off);  off += (size_t)B_N * 4;
    float* dpart = (float*)(ws + off);   off += (size_t)B_N * 4;

    prep_kernel<<<WBLKS + B_N / 4, 256, 0, stream>>>(x, target, ida, bmat, xq, sx,
                                                     wq, sw, dpart, tlogit, rowsum);
    gemm_lse_kernel<<<MT_ * NT_, 512, 0, stream>>>(xq, wq, sx, sw, rowsum);
    rowfin_final_kernel<<<1, 1024, 0, stream>>>(rowsum, tlogit, dpart, out);
}